// Round 20
// baseline (48.478 us; speedup 1.0000x reference)
//
#include <hip/hip_runtime.h>

// Legendre2 v19: v17b (47.3us, PASSING) + two compiler-mediated VALU trims.
//  (1) folds as f32x2 vector C arithmetic -> LLVM lowers contracted v2f32
//      mul-sub to v_pk_fma_f32 (neg modifier) itself; NO hand asm in the
//      MFMA dataflow (v18's hand pk_fma exploded 4.6e23 -- lesson learned).
//      Tables byte-identical to v17b -> absmax must be exactly 16777220.
//  (2) epilogue f32->bf16 via v_cvt_pk_bf16_f32 (T12-verified pattern, HW
//      RNE == f2bf): ~300 -> 32 VALU/iter. Inputs come from LDS, not MFMA.
// Rest = v17b: 256 blk x 512 thr, 2-tile B-frag sharing, chained k-half
// MFMA, setprio, cvt_pkrtz z-convert, scaled recurrence (Q_i = P_i/c_i,
// fold = single fma), single-term f16 chain + bf16 epilogue.
// N=524288, D=64, K=64, O=32, DEGREE=6.

typedef _Float16 f16x8 __attribute__((ext_vector_type(8)));
typedef __fp16   h16x2 __attribute__((ext_vector_type(2)));
typedef short    s16x8 __attribute__((ext_vector_type(8)));
typedef float    f32x4 __attribute__((ext_vector_type(4)));
typedef float    f32x2 __attribute__((ext_vector_type(2)));
struct f32x2p { f32x2 lo, hi; };

#define NN      524288
#define BLOCKS  256
#define THREADS 512
#define NWAVES  8
#define NITER   4                        // 4 x 64-row (2-tile) passes per wave

// LDS byte offsets
#define BH_OFF    0                      // 48 frags * 1 KB (f16 of A, scaled)
#define CF_OFF    49152                  // 4 frags * 1 KB (bf16 of c6*C)
#define SCALE_OFF 53248                  // 384 f32 scales
#define SCR_OFF   54784                  // 8 waves * 4 KB transpose scratch
#define SMEM_BYTES (SCR_OFF + NWAVES * 4096)   // 87552 B

__device__ __forceinline__ unsigned short f2bf(float x) {
    unsigned u = __builtin_bit_cast(unsigned, x);
    return (unsigned short)((u + 0x7FFFu + ((u >> 16) & 1u)) >> 16);
}

__global__ __launch_bounds__(THREADS) void leg_mfma(
    const float* __restrict__ z, const float* __restrict__ T,
    const float* __restrict__ Cm, const float* __restrict__ beta,
    float* __restrict__ out)
{
    extern __shared__ char smem[];
    float* scale_s = (float*)(smem + SCALE_OFF);
    const int tid  = (int)threadIdx.x;
    const int lane = tid & 63;
    const int wv   = tid >> 6;
    const int lrow = lane & 15;          // row (A-op) / col (C/D) index
    const int lhi  = lane >> 4;          // 0..3

    // ---------- phase A: per-row scales with recurrence scaling folded in ---
    // smul[i] = coef_i * s_i (s_i = c_{i-1}/c_i), same as v17b.
    if (tid < 384) {
        const int mat = tid >> 6, kc = tid & 63;
        const float4* tr = (const float4*)(T + (size_t)((mat << 6) + kc) * 64);
        float s = 0.f;
        #pragma unroll
        for (int q = 0; q < 16; ++q) { float4 v = tr[q]; s += v.x + v.y + v.z + v.w; }
        const float smul[6] = {1.f, 3.f, 1.25f, 28.f / 9.f, 81.f / 64.f, 704.f / 225.f};
        const float sc = (mat == 0) ? 1.f : smul[mat] / s;
        scale_s[tid] = sc;
    }
    __syncthreads();

    // ---------- phase B: build B-operand frags of A (f16, scaled) -----------
    for (int g = tid; g < 3072; g += THREADS) {
        const int mat = g >> 9;
        const int s   = (g >> 8) & 1;
        const int f   = (g >> 6) & 3;
        const int l   = g & 63;
        const int kc  = (l & 15) + (f << 4);
        const int d0  = ((l >> 4) << 3) + (s << 5);
        const float sc = scale_s[(mat << 6) + kc];
        const float* src = T + (size_t)((mat << 6) + kc) * 64 + d0;
        const float4 v0 = *(const float4*)(src);
        const float4 v1 = *(const float4*)(src + 4);
        const float vv[8] = {v0.x, v0.y, v0.z, v0.w, v1.x, v1.y, v1.z, v1.w};
        f16x8 hi;
        #pragma unroll
        for (int j = 0; j < 8; ++j) hi[j] = (_Float16)(vv[j] * sc);
        const int fr = (((mat << 1) + s) << 2) + f;
        *(f16x8*)(smem + BH_OFF + fr * 1024 + l * 16) = hi;
    }
    // C-operand frags (bf16, scaled by c6 = 5/16)
    if (tid < 256) {
        const int s  = (tid >> 7) & 1;
        const int fo = (tid >> 6) & 1;
        const int l  = tid & 63;
        const int o  = (l & 15) + (fo << 4);
        const int k0 = ((l >> 4) << 3) + (s << 5);
        const float* src = Cm + (size_t)o * 64 + k0;
        const float4 v0 = *(const float4*)src;
        const float4 v1 = *(const float4*)(src + 4);
        const float vv[8] = {v0.x, v0.y, v0.z, v0.w, v1.x, v1.y, v1.z, v1.w};
        s16x8 fr;
        #pragma unroll
        for (int j = 0; j < 8; ++j) fr[j] = (short)f2bf(vv[j] * 0.3125f);
        *(s16x8*)(smem + CF_OFF + ((s << 1) + fo) * 1024 + l * 16) = fr;
    }
    __syncthreads();

    // ---------- main: each wave owns 256 rows, 4 iters of 64 rows -----------
    const int    gw      = blockIdx.x * NWAVES + wv;
    const size_t rowbase = (size_t)gw * 256;
    float* scr = (float*)(smem + SCR_OFF + wv * 4096);

    const float beta0 = beta[lrow];
    const float beta1 = beta[16 + lrow];
    const f32x2 one2 = {1.f, 1.f};

    f16x8 zh[2][2][2];                   // [u][t][s]

    // one Legendre level (scaled): PT := a (.) PC - PT, as v2f32 so the
    // compiler selects v_pk_fma_f32 (neg-src2 modifier) itself.
    auto leg_step = [&](int mat, f32x4 (&PC)[2][2][4], f32x4 (&PT)[2][2][4]) {
        __builtin_amdgcn_s_setprio(1);
        #pragma unroll
        for (int f = 0; f < 4; ++f) {
            const int fr0 = mat * 8 + f;       // s=0
            const int fr1 = mat * 8 + 4 + f;   // s=1
            const f16x8 bh0 = *(const f16x8*)(smem + BH_OFF + fr0 * 1024 + lane * 16);
            const f16x8 bh1 = *(const f16x8*)(smem + BH_OFF + fr1 * 1024 + lane * 16);
            #pragma unroll
            for (int u = 0; u < 2; ++u)
                #pragma unroll
                for (int t = 0; t < 2; ++t) {
                    f32x4 a = {0.f, 0.f, 0.f, 0.f};
                    a = __builtin_amdgcn_mfma_f32_16x16x32_f16(zh[u][t][0], bh0, a, 0, 0, 0);
                    a = __builtin_amdgcn_mfma_f32_16x16x32_f16(zh[u][t][1], bh1, a, 0, 0, 0);
                    f32x2p av = __builtin_bit_cast(f32x2p, a);
                    f32x2p pc = __builtin_bit_cast(f32x2p, PC[u][t][f]);
                    f32x2p pt = __builtin_bit_cast(f32x2p, PT[u][t][f]);
                    pt.lo = av.lo * pc.lo - pt.lo;     // contracts to pk fma
                    pt.hi = av.hi * pc.hi - pt.hi;
                    PT[u][t][f] = __builtin_bit_cast(f32x4, pt);
                }
        }
        __builtin_amdgcn_s_setprio(0);
    };

    for (int it = 0; it < NITER; ++it) {
        // load + convert z (packed RTZ: 4 cvt_pkrtz per 8 elems)
        #pragma unroll
        for (int u = 0; u < 2; ++u)
            #pragma unroll
            for (int t = 0; t < 2; ++t)
                #pragma unroll
                for (int s = 0; s < 2; ++s) {
                    const float* p = z + (rowbase + (size_t)it * 64 + u * 32 + t * 16 + lrow) * 64
                                       + (s << 5) + (lhi << 3);
                    const float4 q0 = *(const float4*)(p);
                    const float4 q1 = *(const float4*)(p + 4);
                    union { f16x8 v; h16x2 h[4]; } uz;
                    uz.h[0] = __builtin_amdgcn_cvt_pkrtz(q0.x, q0.y);
                    uz.h[1] = __builtin_amdgcn_cvt_pkrtz(q0.z, q0.w);
                    uz.h[2] = __builtin_amdgcn_cvt_pkrtz(q1.x, q1.y);
                    uz.h[3] = __builtin_amdgcn_cvt_pkrtz(q1.z, q1.w);
                    zh[u][t][s] = uz.v;
                }

        // Scaled Legendre chain: pA = Q1, pB = Q2, ping-pong; Q6 ends in pB
        f32x4 pA[2][2][4], pB[2][2][4];
        // mat 0 -> pA  (Q1), chained
        __builtin_amdgcn_s_setprio(1);
        #pragma unroll
        for (int f = 0; f < 4; ++f) {
            const int fr0 = f, fr1 = 4 + f;
            const f16x8 bh0 = *(const f16x8*)(smem + BH_OFF + fr0 * 1024 + lane * 16);
            const f16x8 bh1 = *(const f16x8*)(smem + BH_OFF + fr1 * 1024 + lane * 16);
            #pragma unroll
            for (int u = 0; u < 2; ++u)
                #pragma unroll
                for (int t = 0; t < 2; ++t) {
                    f32x4 a = {0.f, 0.f, 0.f, 0.f};
                    a = __builtin_amdgcn_mfma_f32_16x16x32_f16(zh[u][t][0], bh0, a, 0, 0, 0);
                    a = __builtin_amdgcn_mfma_f32_16x16x32_f16(zh[u][t][1], bh1, a, 0, 0, 0);
                    pA[u][t][f] = a;
                }
        }
        // mat 1 -> pB = Q2 = a (.) Q1 - 1  (Q0 = ones), v2f32 form
        #pragma unroll
        for (int f = 0; f < 4; ++f) {
            const int fr0 = 8 + f, fr1 = 12 + f;
            const f16x8 bh0 = *(const f16x8*)(smem + BH_OFF + fr0 * 1024 + lane * 16);
            const f16x8 bh1 = *(const f16x8*)(smem + BH_OFF + fr1 * 1024 + lane * 16);
            #pragma unroll
            for (int u = 0; u < 2; ++u)
                #pragma unroll
                for (int t = 0; t < 2; ++t) {
                    f32x4 a = {0.f, 0.f, 0.f, 0.f};
                    a = __builtin_amdgcn_mfma_f32_16x16x32_f16(zh[u][t][0], bh0, a, 0, 0, 0);
                    a = __builtin_amdgcn_mfma_f32_16x16x32_f16(zh[u][t][1], bh1, a, 0, 0, 0);
                    f32x2p av = __builtin_bit_cast(f32x2p, a);
                    f32x2p pa = __builtin_bit_cast(f32x2p, pA[u][t][f]);
                    f32x2p pb;
                    pb.lo = av.lo * pa.lo - one2;
                    pb.hi = av.hi * pa.hi - one2;
                    pB[u][t][f] = __builtin_bit_cast(f32x4, pb);
                }
        }
        __builtin_amdgcn_s_setprio(0);
        leg_step(2, pB, pA);   // Q3
        leg_step(3, pA, pB);   // Q4
        leg_step(4, pB, pA);   // Q5
        leg_step(5, pA, pB);   // Q6 = pB

        // ---------------- epilogue: out = Q6 @ (c6*C)^T + beta --------------
        s16x8 ch[2][2];   // [s][fo]
        #pragma unroll
        for (int s = 0; s < 2; ++s)
            #pragma unroll
            for (int fo = 0; fo < 2; ++fo)
                ch[s][fo] = *(const s16x8*)(smem + CF_OFF + ((s << 1) + fo) * 1024 + lane * 16);
        #pragma unroll
        for (int u = 0; u < 2; ++u)
            #pragma unroll
            for (int t = 0; t < 2; ++t) {
                // transpose Q6 (C/D layout) -> A-op layout via XOR-swizzled scratch
                #pragma unroll
                for (int f = 0; f < 4; ++f)
                    #pragma unroll
                    for (int r = 0; r < 4; ++r) {
                        const int row = lhi * 4 + r;
                        const int k   = (f << 4) + lrow;
                        const int g4  = (k >> 2) ^ row;        // group swizzle
                        scr[row * 64 + g4 * 4 + (k & 3)] = pB[u][t][f][r];
                    }
                s16x8 p6h[2];
                #pragma unroll
                for (int s = 0; s < 2; ++s) {
                    const int g0 = lhi * 2 + s * 8;
                    const float4 q0 = *(const float4*)(scr + lrow * 64 + ((g0)     ^ lrow) * 4);
                    const float4 q1 = *(const float4*)(scr + lrow * 64 + ((g0 + 1) ^ lrow) * 4);
                    const float vv[8] = {q0.x, q0.y, q0.z, q0.w, q1.x, q1.y, q1.z, q1.w};
                    union { s16x8 v; unsigned w[4]; } ph;
                    #pragma unroll
                    for (int m = 0; m < 4; ++m)
                        asm("v_cvt_pk_bf16_f32 %0, %1, %2"
                            : "=v"(ph.w[m]) : "v"(vv[2 * m]), "v"(vv[2 * m + 1]));
                    p6h[s] = ph.v;
                }
                #pragma unroll
                for (int fo = 0; fo < 2; ++fo) {
                    f32x4 o = {0.f, 0.f, 0.f, 0.f};
                    o = __builtin_amdgcn_mfma_f32_16x16x32_bf16(p6h[0], ch[0][fo], o, 0, 0, 0);
                    o = __builtin_amdgcn_mfma_f32_16x16x32_bf16(p6h[1], ch[1][fo], o, 0, 0, 0);
                    const float bb = fo ? beta1 : beta0;
                    const size_t r0 = rowbase + (size_t)it * 64 + u * 32 + t * 16 + lhi * 4;
                    #pragma unroll
                    for (int r = 0; r < 4; ++r)
                        out[(r0 + r) * 32 + (fo << 4) + lrow] = o[r] + bb;
                }
            }
    }
}

extern "C" void kernel_launch(void* const* d_in, const int* in_sizes, int n_in,
                              void* d_out, int out_size, void* d_ws, size_t ws_size,
                              hipStream_t stream) {
    const float* z    = (const float*)d_in[0];
    const float* T    = (const float*)d_in[1];
    const float* C    = (const float*)d_in[2];
    const float* beta = (const float*)d_in[3];
    float* out = (float*)d_out;
    (void)in_sizes; (void)n_in; (void)out_size; (void)d_ws; (void)ws_size;

    hipFuncSetAttribute((const void*)leg_mfma,
                        hipFuncAttributeMaxDynamicSharedMemorySize, SMEM_BYTES);
    leg_mfma<<<BLOCKS, THREADS, SMEM_BYTES, stream>>>(z, T, C, beta, out);
}